// Round 1
// baseline (610.599 us; speedup 1.0000x reference)
//
#include <hip/hip_runtime.h>
#include <hip/hip_bf16.h>
#include <cmath>

// Problem constants
#define B_SZ 256
#define NH   16
#define D_SZ 128
#define HID  2048
#define N3   6144   // 3*HID

typedef float    f4 __attribute__((ext_vector_type(4)));
typedef _Float16 h8 __attribute__((ext_vector_type(8)));
typedef _Float16 h4 __attribute__((ext_vector_type(4)));
typedef _Float16 h2 __attribute__((ext_vector_type(2)));

// ---------------------------------------------------------------------------
// Kernel 1: split x (f32) into fp16 hi/lo pair (for fp16x3 exact-ish GEMM)
// ---------------------------------------------------------------------------
__global__ __launch_bounds__(256) void k_split_x(const float* __restrict__ x,
                                                 _Float16* __restrict__ xh,
                                                 _Float16* __restrict__ xl) {
  int i = (blockIdx.x * 256 + threadIdx.x) * 4;
  f4 v = *(const f4*)&x[i];
  h4 H, L;
  #pragma unroll
  for (int j = 0; j < 4; ++j) {
    _Float16 hi = (_Float16)v[j];
    H[j] = hi;
    L[j] = (_Float16)(v[j] - (float)hi);
  }
  *(h4*)&xh[i] = H;
  *(h4*)&xl[i] = L;
}

// ---------------------------------------------------------------------------
// Kernel 2: gates GEMM  [256 x 6144] = x[256x2048] @ W_i[2048x6144] + b_i,
// fp16 hi/lo x3 MFMA (f32-accurate), fused exp/exp/sigmoid epilogue.
// BM=128 BN=64 BK=32, 4 waves (2Mx2N), wave tile 64x32, frags Mf=4 Nf=2.
// LDS rows padded to 40 fp16 (80B) + chunk-XOR swizzle: <=2-way conflicts.
// ---------------------------------------------------------------------------
__device__ __forceinline__ int swz(int row, int ch) {
  return row * 40 + ((ch ^ ((row >> 3) & 3)) << 3);
}

__global__ __launch_bounds__(256) void k_gemm(const _Float16* __restrict__ xh,
                                              const _Float16* __restrict__ xl,
                                              const float* __restrict__ W,
                                              const float* __restrict__ bi,
                                              float* __restrict__ out) {
  __shared__ _Float16 Ah[128 * 40], Al[128 * 40], Bh[64 * 40], Bl[64 * 40];
  const int t  = threadIdx.x;
  const int n0 = blockIdx.x * 64;
  const int m0 = blockIdx.y * 128;
  const int w  = t >> 6, l = t & 63;
  const int wm = (w >> 1) * 64, wn = (w & 1) * 32;
  const int fr = l & 15, fc = l >> 4;

  // A staging: thread -> (row, 2 chunks of 8 fp16)
  const int ar = t >> 1, ac0 = (t & 1) * 2;
  const _Float16* gxh = xh + (size_t)(m0 + ar) * HID + ac0 * 8;
  const _Float16* gxl = xl + (size_t)(m0 + ar) * HID + ac0 * 8;
  // B staging: thread -> (k-pair p, n-quad nq); reads W rows, writes transposed
  const int p = t >> 4, nq = t & 15;
  const float* gw = W + (size_t)(2 * p) * N3 + n0 + nq * 4;

  f4 acc[4][2];
  #pragma unroll
  for (int a = 0; a < 4; ++a)
    #pragma unroll
    for (int c = 0; c < 2; ++c) { f4 z = {0.f, 0.f, 0.f, 0.f}; acc[a][c] = z; }

  for (int kt = 0; kt < 64; ++kt) {
    const int k0 = kt * 32;
    h8 va0 = *(const h8*)(gxh + k0);
    h8 va1 = *(const h8*)(gxh + k0 + 8);
    h8 vl0 = *(const h8*)(gxl + k0);
    h8 vl1 = *(const h8*)(gxl + k0 + 8);
    f4 r0 = *(const f4*)(gw + (size_t)k0 * N3);
    f4 r1 = *(const f4*)(gw + (size_t)(k0 + 1) * N3);
    __syncthreads();  // protect previous iteration's fragment reads
    *(h8*)&Ah[swz(ar, ac0)]     = va0;
    *(h8*)&Ah[swz(ar, ac0 + 1)] = va1;
    *(h8*)&Al[swz(ar, ac0)]     = vl0;
    *(h8*)&Al[swz(ar, ac0 + 1)] = vl1;
    #pragma unroll
    for (int i2 = 0; i2 < 4; ++i2) {
      int n = nq * 4 + i2;
      _Float16 h0 = (_Float16)r0[i2]; _Float16 l0v = (_Float16)(r0[i2] - (float)h0);
      _Float16 h1 = (_Float16)r1[i2]; _Float16 l1v = (_Float16)(r1[i2] - (float)h1);
      int e = n * 40 + ((((2 * p) >> 3) ^ ((n >> 3) & 3)) << 3) + ((2 * p) & 7);
      h2 vh = {h0, h1};  *(h2*)&Bh[e] = vh;
      h2 vl = {l0v, l1v}; *(h2*)&Bl[e] = vl;
    }
    __syncthreads();
    h8 a_h[4], a_l[4], b_h[2], b_l[2];
    #pragma unroll
    for (int mi = 0; mi < 4; ++mi) {
      int r = wm + mi * 16 + fr;
      a_h[mi] = *(const h8*)&Ah[swz(r, fc)];
      a_l[mi] = *(const h8*)&Al[swz(r, fc)];
    }
    #pragma unroll
    for (int ni = 0; ni < 2; ++ni) {
      int c = wn + ni * 16 + fr;
      b_h[ni] = *(const h8*)&Bh[swz(c, fc)];
      b_l[ni] = *(const h8*)&Bl[swz(c, fc)];
    }
    #pragma unroll
    for (int mi = 0; mi < 4; ++mi)
      #pragma unroll
      for (int ni = 0; ni < 2; ++ni) {
        acc[mi][ni] = __builtin_amdgcn_mfma_f32_16x16x32_f16(a_h[mi], b_h[ni], acc[mi][ni], 0, 0, 0);
        acc[mi][ni] = __builtin_amdgcn_mfma_f32_16x16x32_f16(a_h[mi], b_l[ni], acc[mi][ni], 0, 0, 0);
        acc[mi][ni] = __builtin_amdgcn_mfma_f32_16x16x32_f16(a_l[mi], b_h[ni], acc[mi][ni], 0, 0, 0);
      }
  }
  // Epilogue: bias + activation (block's 64-col range never straddles gate
  // boundaries since 2048 % 64 == 0 -> uniform branch)
  #pragma unroll
  for (int mi = 0; mi < 4; ++mi)
    #pragma unroll
    for (int ni = 0; ni < 2; ++ni)
      #pragma unroll
      for (int r2 = 0; r2 < 4; ++r2) {
        int m = m0 + wm + mi * 16 + fc * 4 + r2;  // C/D: row=(lane>>4)*4+reg
        int n = n0 + wn + ni * 16 + fr;           //       col=lane&15
        float v = acc[mi][ni][r2] + bi[n];
        out[(size_t)m * N3 + n] = (n < 4096) ? expf(v) : 1.0f / (1.0f + expf(-v));
      }
}

// ---------------------------------------------------------------------------
// Kernel 3: fused qkv projection + mLSTM recurrence + C stream.
// One block per (b,h): reads C tile once, writes C_new once.
// ---------------------------------------------------------------------------
__global__ __launch_bounds__(256) void k_rec(const float* __restrict__ x,
                                             const float* __restrict__ C,
                                             const float* __restrict__ nin,
                                             const float* __restrict__ Wq,
                                             const float* __restrict__ bq,
                                             const float* __restrict__ gates,
                                             float* __restrict__ oh,
                                             float* __restrict__ oC,
                                             float* __restrict__ on) {
  __shared__ float x_s[128], q_s[128], k_s[128], v_s[128], f_s[128], iv_s[128], o_s[128];
  __shared__ float red[4];
  __shared__ float den_s;
  const int t = threadIdx.x;
  const int h = blockIdx.x >> 8, b = blockIdx.x & 255;  // h-major: W_qkv L2 reuse
  const int bh = b * NH + h;

  if (t < 32) *(f4*)&x_s[t * 4] = *(const f4*)&x[(size_t)b * HID + h * D_SZ + t * 4];
  float i_r = 0.f, f_r = 0.f, o_r = 0.f, n_r = 0.f;
  if (t < 128) {
    const float* g = gates + (size_t)b * N3 + h * D_SZ + t;
    i_r = g[0]; f_r = g[2048]; o_r = g[4096];
    n_r = nin[(size_t)bh * D_SZ + t];
  }
  __syncthreads();

  // qkv: per-head [1x128] @ [128x384]; columns assigned to lanes (coalesced)
  for (int nn = t; nn < 384; nn += 256) {
    float acc = bq[h * 384 + nn];
    const float* wp = Wq + (size_t)h * D_SZ * 384 + nn;
    #pragma unroll 8
    for (int kk = 0; kk < 128; ++kk) acc = fmaf(x_s[kk], wp[(size_t)kk * 384], acc);
    if (nn < 128)      q_s[nn] = acc;
    else if (nn < 256) k_s[nn - 128] = acc * 0.088388347648318447f;  // 1/sqrt(128)
    else               v_s[nn - 256] = acc;
  }
  __syncthreads();

  float part = 0.f;
  if (t < 128) {
    float nnew = fmaf(f_r, n_r, i_r * k_s[t]);
    on[(size_t)bh * D_SZ + t] = nnew;
    f_s[t] = f_r; iv_s[t] = i_r * v_s[t]; o_s[t] = o_r;
    part = nnew * q_s[t];
  }
  part += __shfl_xor(part, 1);  part += __shfl_xor(part, 2);
  part += __shfl_xor(part, 4);  part += __shfl_xor(part, 8);
  part += __shfl_xor(part, 16); part += __shfl_xor(part, 32);
  if ((t & 63) == 0) red[t >> 6] = part;
  __syncthreads();
  if (t == 0) den_s = fmaxf(fabsf(red[0] + red[1] + red[2] + red[3]), 1.0f);
  __syncthreads();
  const float den = den_s;

  // Stream C: 2 rows per wave-iter (half-wave per row, float4 per lane)
  const int w = t >> 6, l = t & 63, half = l >> 5, li = l & 31;
  const size_t base = (size_t)bh * (D_SZ * D_SZ);
  #pragma unroll 2
  for (int it = 0; it < 16; ++it) {
    const int row = w * 32 + it * 2 + half;
    const size_t off = base + (size_t)row * D_SZ + li * 4;
    f4 c4 = *(const f4*)&C[off];
    f4 q4 = *(const f4*)&q_s[li * 4];
    float dp = c4[0] * q4[0] + c4[1] * q4[1] + c4[2] * q4[2] + c4[3] * q4[3];
    dp += __shfl_xor(dp, 1); dp += __shfl_xor(dp, 2); dp += __shfl_xor(dp, 4);
    dp += __shfl_xor(dp, 8); dp += __shfl_xor(dp, 16);   // 32-lane half reduce
    const float fr2 = f_s[row], ivr = iv_s[row];
    f4 k4 = *(const f4*)&k_s[li * 4];
    f4 cn = { fr2 * c4[0] + ivr * k4[0], fr2 * c4[1] + ivr * k4[1],
              fr2 * c4[2] + ivr * k4[2], fr2 * c4[3] + ivr * k4[3] };
    *(f4*)&oC[off] = cn;
    if (li == 0) oh[(size_t)b * HID + h * D_SZ + row] = o_s[row] * dp / den;
  }
}

// ---------------------------------------------------------------------------
extern "C" void kernel_launch(void* const* d_in, const int* in_sizes, int n_in,
                              void* d_out, int out_size, void* d_ws, size_t ws_size,
                              hipStream_t stream) {
  const float* x     = (const float*)d_in[0];
  // d_in[1] (h) is unused by the reference
  const float* Cst   = (const float*)d_in[2];
  const float* n_st  = (const float*)d_in[3];
  const float* W_i   = (const float*)d_in[4];
  const float* b_i   = (const float*)d_in[5];
  const float* W_qkv = (const float*)d_in[6];
  const float* b_qkv = (const float*)d_in[7];

  float* out   = (float*)d_out;
  float* out_h = out;                        // [256*2048]
  float* out_C = out + 524288;               // [256*16*128*128]
  float* out_n = out + 524288 + 67108864;    // [256*16*128]

  float*    gates = (float*)d_ws;                                  // 6,291,456 B
  _Float16* xh    = (_Float16*)((char*)d_ws + 6291456);            // 1 MB
  _Float16* xl    = (_Float16*)((char*)d_ws + 7340032);            // 1 MB

  k_split_x<<<512, 256, 0, stream>>>(x, xh, xl);
  k_gemm<<<dim3(96, 2), 256, 0, stream>>>(xh, xl, W_i, b_i, gates);
  k_rec<<<4096, 256, 0, stream>>>(x, Cst, n_st, W_qkv, b_qkv, gates, out_h, out_C, out_n);
}

// Round 2
// 541.335 us; speedup vs baseline: 1.1280x; 1.1280x over previous
//
#include <hip/hip_runtime.h>
#include <hip/hip_bf16.h>
#include <cmath>

#define NH   16
#define D_SZ 128
#define HID  2048
#define N3   6144   // 3*HID

typedef float    f4 __attribute__((ext_vector_type(4)));
typedef float    f2 __attribute__((ext_vector_type(2)));
typedef _Float16 h8 __attribute__((ext_vector_type(8)));
typedef _Float16 h2 __attribute__((ext_vector_type(2)));

// padded-row (40 halfwords) + chunk-XOR swizzle LDS layout, <=2-way conflicts
__device__ __forceinline__ int swz(int row, int ch) {
  return row * 40 + ((ch ^ ((row >> 3) & 3)) << 3);
}

// ---------------------------------------------------------------------------
// Kernel 1: gates GEMM [256x6144] = x[256x2048] @ W_i + b_i, fp16 hi/lo x3
// MFMA, fused exp/sigmoid epilogue. BM=128 BN=32 BK=32, grid (192,2)=384
// blocks. Register prefetch of iter k+1 issued before the MFMA section.
// ---------------------------------------------------------------------------
__global__ __launch_bounds__(256) void k_gemm(const float* __restrict__ x,
                                              const float* __restrict__ W,
                                              const float* __restrict__ bi,
                                              float* __restrict__ out) {
  __shared__ _Float16 Ah[128 * 40], Al[128 * 40], Bh[32 * 40], Bl[32 * 40];
  const int t  = threadIdx.x;
  const int n0 = blockIdx.x * 32;
  const int m0 = blockIdx.y * 128;
  const int w  = t >> 6, l = t & 63;
  const int wm = (w >> 1) * 64, wn = (w & 1) * 16;
  const int fr = l & 15, fc = l >> 4;

  // A staging: thread -> (row, 2 h8-chunks); loads x f32, converts hi/lo
  const int ar = t >> 1, ac0 = (t & 1) * 2;
  const float* gx = x + (size_t)(m0 + ar) * HID + ac0 * 8;
  // B staging: thread -> (k-row pair 2rp/2rp+1, col pair cq*2..+1)
  const int rp = t >> 4, cq = t & 15;
  const float* gw = W + (size_t)(2 * rp) * N3 + n0 + cq * 2;

  f4 acc[4];
  #pragma unroll
  for (int i = 0; i < 4; ++i) { f4 z = {0.f, 0.f, 0.f, 0.f}; acc[i] = z; }

  f4 ra0, ra1, ra2, ra3;  // prefetched x (16 floats)
  f2 rb0, rb1;            // prefetched W rows 2rp, 2rp+1 (2 cols)
  ra0 = *(const f4*)(gx);      ra1 = *(const f4*)(gx + 4);
  ra2 = *(const f4*)(gx + 8);  ra3 = *(const f4*)(gx + 12);
  rb0 = *(const f2*)(gw);      rb1 = *(const f2*)(gw + N3);

  for (int kt = 0; kt < 64; ++kt) {
    __syncthreads();  // previous iteration's fragment reads complete
    // stage A (hi/lo split)
    h8 H0, L0, H1, L1;
    #pragma unroll
    for (int j = 0; j < 4; ++j) {
      _Float16 hh;
      hh = (_Float16)ra0[j]; H0[j]     = hh; L0[j]     = (_Float16)(ra0[j] - (float)hh);
      hh = (_Float16)ra1[j]; H0[j + 4] = hh; L0[j + 4] = (_Float16)(ra1[j] - (float)hh);
      hh = (_Float16)ra2[j]; H1[j]     = hh; L1[j]     = (_Float16)(ra2[j] - (float)hh);
      hh = (_Float16)ra3[j]; H1[j + 4] = hh; L1[j + 4] = (_Float16)(ra3[j] - (float)hh);
    }
    *(h8*)&Ah[swz(ar, ac0)]     = H0;
    *(h8*)&Ah[swz(ar, ac0 + 1)] = H1;
    *(h8*)&Al[swz(ar, ac0)]     = L0;
    *(h8*)&Al[swz(ar, ac0 + 1)] = L1;
    // stage B transposed [n][k] (hi/lo split), h2 packs k-pair
    #pragma unroll
    for (int i = 0; i < 2; ++i) {
      float w0 = rb0[i], w1 = rb1[i];
      _Float16 h0 = (_Float16)w0, h1 = (_Float16)w1;
      int n = cq * 2 + i, k = 2 * rp;
      int e = n * 40 + (((k >> 3) ^ ((n >> 3) & 3)) << 3) + (k & 7);
      h2 vh = {h0, h1};
      *(h2*)&Bh[e] = vh;
      h2 vl = {(_Float16)(w0 - (float)h0), (_Float16)(w1 - (float)h1)};
      *(h2*)&Bl[e] = vl;
    }
    __syncthreads();
    if (kt < 63) {  // prefetch next iteration; flies under fragment reads+MFMA
      const int k0 = (kt + 1) * 32;
      ra0 = *(const f4*)(gx + k0);      ra1 = *(const f4*)(gx + k0 + 4);
      ra2 = *(const f4*)(gx + k0 + 8);  ra3 = *(const f4*)(gx + k0 + 12);
      rb0 = *(const f2*)(gw + (size_t)k0 * N3);
      rb1 = *(const f2*)(gw + (size_t)(k0 + 1) * N3);
    }
    h8 a_h[4], a_l[4], b_h, b_l;
    #pragma unroll
    for (int mi = 0; mi < 4; ++mi) {
      int r = wm + mi * 16 + fr;
      a_h[mi] = *(const h8*)&Ah[swz(r, fc)];
      a_l[mi] = *(const h8*)&Al[swz(r, fc)];
    }
    { int c = wn + fr; b_h = *(const h8*)&Bh[swz(c, fc)]; b_l = *(const h8*)&Bl[swz(c, fc)]; }
    #pragma unroll
    for (int mi = 0; mi < 4; ++mi) {
      acc[mi] = __builtin_amdgcn_mfma_f32_16x16x32_f16(a_h[mi], b_h, acc[mi], 0, 0, 0);
      acc[mi] = __builtin_amdgcn_mfma_f32_16x16x32_f16(a_h[mi], b_l, acc[mi], 0, 0, 0);
      acc[mi] = __builtin_amdgcn_mfma_f32_16x16x32_f16(a_l[mi], b_h, acc[mi], 0, 0, 0);
    }
  }
  // epilogue: bias + activation
  #pragma unroll
  for (int mi = 0; mi < 4; ++mi)
    #pragma unroll
    for (int r2 = 0; r2 < 4; ++r2) {
      int m = m0 + wm + mi * 16 + fc * 4 + r2;  // C/D: row=(lane>>4)*4+reg
      int n = n0 + wn + fr;                     //      col=lane&15
      float v = acc[mi][r2] + bi[n];
      out[(size_t)m * N3 + n] = (n < 4096) ? expf(v) : 1.0f / (1.0f + expf(-v));
    }
}

// ---------------------------------------------------------------------------
// Kernel 2: qkv projection, 16 independent [256x128]@[128x384] GEMMs,
// fp16 hi/lo x3 MFMA. BM=64 BN=64 BK=32, grid (16,4,6)=384 blocks.
// Writes q/k/v (k pre-scaled by 1/sqrt(D)) to workspace.
// ---------------------------------------------------------------------------
__global__ __launch_bounds__(256) void k_qkv(const float* __restrict__ x,
                                             const float* __restrict__ Wq,
                                             const float* __restrict__ bq,
                                             float* __restrict__ q_ws,
                                             float* __restrict__ k_ws,
                                             float* __restrict__ v_ws) {
  __shared__ _Float16 Ah[64 * 40], Al[64 * 40], Bh[64 * 40], Bl[64 * 40];
  const int t  = threadIdx.x;
  const int h  = blockIdx.x;
  const int m0 = blockIdx.y * 64;
  const int n0 = blockIdx.z * 64;
  const int w  = t >> 6, l = t & 63;
  const int wm = (w >> 1) * 32, wn = (w & 1) * 32;
  const int fr = l & 15, fc = l >> 4;

  const int ar = t >> 2, ac = t & 3;   // A: 64 rows x 4 h8-chunks
  const float* gx = x + (size_t)(m0 + ar) * HID + h * D_SZ + ac * 8;
  const int rp = t >> 4, cq = t & 15;  // B: k-pair 2rp, cols cq*4..+3
  const float* gw = Wq + (size_t)h * D_SZ * 384 + (size_t)(2 * rp) * 384 + n0 + cq * 4;

  f4 acc[2][2];
  #pragma unroll
  for (int a = 0; a < 2; ++a)
    #pragma unroll
    for (int c = 0; c < 2; ++c) { f4 z = {0.f, 0.f, 0.f, 0.f}; acc[a][c] = z; }

  for (int kk = 0; kk < 4; ++kk) {
    const int k0 = kk * 32;
    f4 a0 = *(const f4*)(gx + k0);
    f4 a1 = *(const f4*)(gx + k0 + 4);
    f4 rb0 = *(const f4*)(gw + (size_t)k0 * 384);
    f4 rb1 = *(const f4*)(gw + (size_t)(k0 + 1) * 384);
    __syncthreads();
    h8 H, L;
    #pragma unroll
    for (int j = 0; j < 4; ++j) {
      _Float16 hh;
      hh = (_Float16)a0[j]; H[j]     = hh; L[j]     = (_Float16)(a0[j] - (float)hh);
      hh = (_Float16)a1[j]; H[j + 4] = hh; L[j + 4] = (_Float16)(a1[j] - (float)hh);
    }
    *(h8*)&Ah[swz(ar, ac)] = H;
    *(h8*)&Al[swz(ar, ac)] = L;
    #pragma unroll
    for (int i = 0; i < 4; ++i) {
      float w0 = rb0[i], w1 = rb1[i];
      _Float16 h0 = (_Float16)w0, h1 = (_Float16)w1;
      int n = cq * 4 + i, k = 2 * rp;
      int e = n * 40 + (((k >> 3) ^ ((n >> 3) & 3)) << 3) + (k & 7);
      h2 vh = {h0, h1};
      *(h2*)&Bh[e] = vh;
      h2 vl = {(_Float16)(w0 - (float)h0), (_Float16)(w1 - (float)h1)};
      *(h2*)&Bl[e] = vl;
    }
    __syncthreads();
    h8 a_h[2], a_l[2], b_h[2], b_l[2];
    #pragma unroll
    for (int mi = 0; mi < 2; ++mi) {
      int r = wm + mi * 16 + fr;
      a_h[mi] = *(const h8*)&Ah[swz(r, fc)];
      a_l[mi] = *(const h8*)&Al[swz(r, fc)];
    }
    #pragma unroll
    for (int ni = 0; ni < 2; ++ni) {
      int c = wn + ni * 16 + fr;
      b_h[ni] = *(const h8*)&Bh[swz(c, fc)];
      b_l[ni] = *(const h8*)&Bl[swz(c, fc)];
    }
    #pragma unroll
    for (int mi = 0; mi < 2; ++mi)
      #pragma unroll
      for (int ni = 0; ni < 2; ++ni) {
        acc[mi][ni] = __builtin_amdgcn_mfma_f32_16x16x32_f16(a_h[mi], b_h[ni], acc[mi][ni], 0, 0, 0);
        acc[mi][ni] = __builtin_amdgcn_mfma_f32_16x16x32_f16(a_h[mi], b_l[ni], acc[mi][ni], 0, 0, 0);
        acc[mi][ni] = __builtin_amdgcn_mfma_f32_16x16x32_f16(a_l[mi], b_h[ni], acc[mi][ni], 0, 0, 0);
      }
  }
  #pragma unroll
  for (int mi = 0; mi < 2; ++mi)
    #pragma unroll
    for (int ni = 0; ni < 2; ++ni)
      #pragma unroll
      for (int r2 = 0; r2 < 4; ++r2) {
        int m = m0 + wm + mi * 16 + fc * 4 + r2;   // global batch row
        int n = n0 + wn + ni * 16 + fr;            // 0..383 within head
        float v = acc[mi][ni][r2] + bq[h * 384 + n];
        size_t bh = (size_t)m * NH + h;
        if (n < 128)       q_ws[bh * D_SZ + n] = v;
        else if (n < 256)  k_ws[bh * D_SZ + (n - 128)] = v * 0.088388347648318447f;
        else               v_ws[bh * D_SZ + (n - 256)] = v;
      }
}

// ---------------------------------------------------------------------------
// Kernel 3: pure streaming recurrence. One block per (b,h). Inner loop has
// NO cross-lane ops: dp partials go to a stride-33 (conflict-free) LDS
// buffer, reduced once per block at the end.
// ---------------------------------------------------------------------------
__global__ __launch_bounds__(256) void k_stream(const float* __restrict__ C,
                                                const float* __restrict__ nin,
                                                const float* __restrict__ gates,
                                                const float* __restrict__ q_ws,
                                                const float* __restrict__ k_ws,
                                                const float* __restrict__ v_ws,
                                                float* __restrict__ oh,
                                                float* __restrict__ oC,
                                                float* __restrict__ on) {
  __shared__ float2 fiv_s[128];
  __shared__ float  part_s[128 * 33];
  __shared__ float  red[4];
  __shared__ float  den_s;
  const int t  = threadIdx.x;
  const int bh = blockIdx.x, b = bh >> 4, h = bh & 15;
  const int w  = t >> 6, l = t & 63, half = l >> 5, li = l & 31;

  float o_r = 0.f, part = 0.f;
  if (t < 128) {
    const float* g = gates + (size_t)b * N3 + h * D_SZ + t;
    float i_r = g[0], f_r = g[2048];
    o_r = g[4096];
    float n_r = nin[(size_t)bh * D_SZ + t];
    float k_r = k_ws[(size_t)bh * D_SZ + t];
    float v_r = v_ws[(size_t)bh * D_SZ + t];
    float q_r = q_ws[(size_t)bh * D_SZ + t];
    float nnew = fmaf(f_r, n_r, i_r * k_r);
    on[(size_t)bh * D_SZ + t] = nnew;
    float2 fv; fv.x = f_r; fv.y = i_r * v_r;
    fiv_s[t] = fv;
    part = nnew * q_r;
  }
  f4 q4 = *(const f4*)&q_ws[(size_t)bh * D_SZ + li * 4];
  f4 k4 = *(const f4*)&k_ws[(size_t)bh * D_SZ + li * 4];
  part += __shfl_xor(part, 1);  part += __shfl_xor(part, 2);
  part += __shfl_xor(part, 4);  part += __shfl_xor(part, 8);
  part += __shfl_xor(part, 16); part += __shfl_xor(part, 32);
  if ((t & 63) == 0) red[t >> 6] = part;
  __syncthreads();
  if (t == 0) den_s = fmaxf(fabsf(red[0] + red[1] + red[2] + red[3]), 1.0f);
  __syncthreads();

  // stream: wave w, half -> rows r0..r0+15; lane li -> cols 4li..4li+3
  const int r0 = w * 32 + half * 16;
  const size_t base = (size_t)bh * (D_SZ * D_SZ);
  const float* Cp = C  + base + (size_t)r0 * D_SZ + li * 4;
  float*       Op = oC + base + (size_t)r0 * D_SZ + li * 4;
  #pragma unroll
  for (int it = 0; it < 16; ++it) {
    const int row = r0 + it;
    f4 c4 = __builtin_nontemporal_load((const f4*)(Cp + it * D_SZ));
    float2 fv = fiv_s[row];
    float dp = c4[0] * q4[0] + c4[1] * q4[1] + c4[2] * q4[2] + c4[3] * q4[3];
    part_s[row * 33 + li] = dp;
    f4 cn = { fmaf(fv.x, c4[0], fv.y * k4[0]), fmaf(fv.x, c4[1], fv.y * k4[1]),
              fmaf(fv.x, c4[2], fv.y * k4[2]), fmaf(fv.x, c4[3], fv.y * k4[3]) };
    __builtin_nontemporal_store(cn, (f4*)(Op + it * D_SZ));
  }
  __syncthreads();
  if (t < 128) {
    float dp = 0.f;
    #pragma unroll
    for (int j = 0; j < 32; ++j) dp += part_s[t * 33 + j];
    oh[(size_t)b * HID + h * D_SZ + t] = o_r * dp / den_s;
  }
}

// ---------------------------------------------------------------------------
extern "C" void kernel_launch(void* const* d_in, const int* in_sizes, int n_in,
                              void* d_out, int out_size, void* d_ws, size_t ws_size,
                              hipStream_t stream) {
  const float* x     = (const float*)d_in[0];
  // d_in[1] (h) unused by the reference
  const float* Cst   = (const float*)d_in[2];
  const float* n_st  = (const float*)d_in[3];
  const float* W_i   = (const float*)d_in[4];
  const float* b_i   = (const float*)d_in[5];
  const float* W_qkv = (const float*)d_in[6];
  const float* b_qkv = (const float*)d_in[7];

  float* out   = (float*)d_out;
  float* out_h = out;                        // [256*2048]
  float* out_C = out + 524288;               // [256*16*128*128]
  float* out_n = out + 524288 + 67108864;    // [256*16*128]

  float* gates = (float*)d_ws;                         // 6 MB
  float* q_ws  = (float*)((char*)d_ws + 6291456);      // 2 MB
  float* k_ws  = (float*)((char*)d_ws + 8388608);      // 2 MB
  float* v_ws  = (float*)((char*)d_ws + 10485760);     // 2 MB

  k_gemm<<<dim3(192, 2), 256, 0, stream>>>(x, W_i, b_i, gates);
  k_qkv<<<dim3(16, 4, 6), 256, 0, stream>>>(x, W_qkv, b_qkv, q_ws, k_ws, v_ws);
  k_stream<<<4096, 256, 0, stream>>>(Cst, n_st, gates, q_ws, k_ws, v_ws,
                                     out_h, out_C, out_n);
}